// Round 10
// baseline (101.845 us; speedup 1.0000x reference)
//
#include <hip/hip_runtime.h>
#include <math.h>

typedef __bf16 bf16x8 __attribute__((ext_vector_type(8)));
typedef float  f32x16 __attribute__((ext_vector_type(16)));
typedef float  f32x4v __attribute__((ext_vector_type(4)));

#define CIN    64
#define KOUT   128
#define HGT    128
#define WID    128
#define NBATCH 16
#define BN_EPS 1e-5f

// workspace layout
#define WQ_OFF   256u                        // packed frag weights: 144*64*16B = 147456 B
#define XT_OFF   (1u << 20)                  // NHWC bf16 x: 16*128*128*64*2 = 33554432 B
#define WS_NEED  ((size_t)XT_OFF + (size_t)NBATCH * HGT * WID * CIN * 2)

// ---------------- w_scale = max|W| ------------------------------------------
__global__ __launch_bounds__(256) void wmax_kernel(const float* __restrict__ W,
                                                   unsigned* __restrict__ wsmax) {
    int idx = blockIdx.x * 256 + threadIdx.x;   // 72*256*4 = 73728 floats
    const float4* W4 = (const float4*)W;
    float4 v = W4[idx];
    float m = fmaxf(fmaxf(fabsf(v.x), fabsf(v.y)), fmaxf(fabsf(v.z), fabsf(v.w)));
    #pragma unroll
    for (int off = 32; off > 0; off >>= 1)
        m = fmaxf(m, __shfl_xor(m, off));
    __shared__ float red[4];
    if ((threadIdx.x & 63) == 0) red[threadIdx.x >> 6] = m;
    __syncthreads();
    if (threadIdx.x == 0) {
        m = fmaxf(fmaxf(red[0], red[1]), fmaxf(red[2], red[3]));
        atomicMax(wsmax, __float_as_uint(m));
    }
}

// ---------------- pack weights into MFMA A-fragment order -------------------
// chunk = cs*3 + dx (12 chunks of 12288 B = 768 uint4, gload_lds-stageable).
// frag index within chunk = dy*4 + mf. Global frag f = ((cs*3+dx)*3 + dy)*4 + mf.
// Lane layout per frag (bf16x8): j-th elem = Wq[kout = mf*32 + (lane&31)]
//                                            [c = cs*16 + (lane>>5)*8 + j] at tap (dy,dx).
__global__ __launch_bounds__(256) void pack_w(const float* __restrict__ W,
                                              const unsigned* __restrict__ wsmax,
                                              __bf16* __restrict__ wqp) {
    int bid = blockIdx.x;                       // 36 = cs*9 + tap
    int tap = bid % 9, cs = bid / 9;
    int dy = tap / 3, dx = tap % 3;
    int t = threadIdx.x;
    int lane = t & 63, mf = t >> 6;
    float ws = __uint_as_float(*wsmax) / 127.0f;
    int kout  = mf * 32 + (lane & 31);
    int cbase = cs * 16 + (lane >> 5) * 8;
    bf16x8 o;
    #pragma unroll
    for (int j = 0; j < 8; ++j) {
        float w = W[(size_t)(kout * 64 + cbase + j) * 9 + tap];
        float q = rintf(w / ws);                // RNE == jnp.round
        q = fminf(fmaxf(q, -127.f), 127.f);
        o[j] = (__bf16)q;                       // integer: exact in bf16
    }
    int f = ((cs * 3 + dx) * 3 + dy) * 4 + mf;
    *(bf16x8*)(wqp + ((size_t)f * 64 + lane) * 8) = o;
}

// ---------------- x: NCHW f32 -> NHWC bf16 -----------------------------------
__global__ __launch_bounds__(256) void xform(const float* __restrict__ x,
                                             __bf16* __restrict__ xT) {
    __shared__ float t[CIN * 32];               // 8 KB, xor-swizzled cols
    int bid = blockIdx.x;                       // n*512 + h*4 + wt
    int wt = bid & 3;
    int h  = (bid >> 2) & 127;
    int n  = bid >> 9;
    int w0 = wt * 32;
    int tid = threadIdx.x;
    const float* src = x + ((size_t)n * CIN * HGT + h) * WID + w0;
    int wlane = tid & 31;
    int cbase = tid >> 5;
    #pragma unroll
    for (int it = 0; it < 8; ++it) {
        int c = cbase + it * 8;
        t[c * 32 + (wlane ^ (c & 31))] = src[(size_t)c * HGT * WID + wlane];
    }
    __syncthreads();
    int w = tid >> 3;
    int chunk = tid & 7;
    bf16x8 o;
    #pragma unroll
    for (int j = 0; j < 8; ++j) {
        int c = chunk * 8 + j;
        o[j] = (__bf16)t[c * 32 + (w ^ (c & 31))];
    }
    *(bf16x8*)(xT + (((size_t)n * HGT + h) * WID + w0 + w) * CIN + chunk * 8) = o;
}

// ---------------- conv3x3 via MFMA 32x32x16 bf16 ----------------------------
// block: 512 thr = 8 waves; out tile 8h x 32w x 128 kout; 2 blocks/CU (69 KB LDS).
// 12-phase pipeline (phase = cs*3+dx): weight chunk (p+1) prefetched into the
// OTHER LDS buffer via global_load_lds while phase p computes -> barrier never
// drains a cold load (T3-lite / m97 structure). Accumulation order unchanged.
__global__ __launch_bounds__(512, 4) void conv_mfma(
    const __bf16* __restrict__ xT, const __bf16* __restrict__ wqp,
    const float* __restrict__ gamma, const float* __restrict__ beta,
    const float* __restrict__ mean, const float* __restrict__ var,
    const float* __restrict__ act_scale, const unsigned* __restrict__ wsmax,
    float* __restrict__ out)
{
    __shared__ uint4 xs[2720];                  // halo 43520 B; reused as repack buf
    __shared__ uint4 wl[2][768];                // weight chunk dbuf: 24576 B
    __shared__ float sc2[KOUT], sh2[KOUT];      // 1024 B   (total 69120 B -> 2 blk/CU)

    // XCD-bijective swizzle: nwg = 1024, 8 XCDs, 1024 % 8 == 0
    const int bid0 = blockIdx.x;
    const int bid  = (bid0 & 7) * 128 + (bid0 >> 3);
    const int wb = bid & 3, hb = (bid >> 2) & 15, n = bid >> 6;
    const int h0 = hb * 8, w0 = wb * 32;
    const int tid  = threadIdx.x;
    const int lane = tid & 63;
    const int wave = tid >> 6;
    const int wmf = wave & 3;                   // kout frag (32 kout)
    const int wr  = wave >> 2;                  // row group (4 rows)

    const uint4* wq4 = (const uint4*)wqp;
    // stage chunk c (768 uint4) into buf: 12 x gload_lds of 1 KB (64 lanes x 16B)
    #define STAGE(c, buf)                                                          \
      do {                                                                         \
        const uint4* _src = wq4 + (size_t)(c) * 768;                               \
        uint4* _dst = (buf);                                                       \
        __builtin_amdgcn_global_load_lds((const void*)(_src + wave * 64 + lane),   \
                                         (void*)(_dst + wave * 64), 16, 0, 0);     \
        if (wave < 4)                                                              \
          __builtin_amdgcn_global_load_lds(                                        \
              (const void*)(_src + (8 + wave) * 64 + lane),                        \
              (void*)(_dst + (8 + wave) * 64), 16, 0, 0);                          \
      } while (0)

    // ---- prologue: issue chunk-0 prefetch FIRST (in flight under halo staging) ----
    STAGE(0, wl[0]);

    const float s_act = act_scale[0] / 255.0f;
    if (tid < KOUT) {
        float ws  = __uint_as_float(*wsmax) / 127.0f;
        float isd = 1.0f / sqrtf(var[tid] + BN_EPS);
        float sc  = ws * gamma[tid] * isd;      // fold w_scale into BN scale
        float sh  = beta[tid] - gamma[tid] * mean[tid] * isd;
        sc2[tid] = sc / s_act;                  // q = rint(acc*sc2 + sh2)
        sh2[tid] = sh / s_act;
    }

    // ---- stage halo tile 10 x 34 px x 64 ch, chunk-xor swizzle (write==read) ----
    const __bf16* xn = xT + (size_t)n * HGT * WID * CIN;
    for (int it = tid; it < 2720; it += 512) {
        int pl = it >> 3, chunk = it & 7;
        int r = pl / 34, cc = pl - r * 34;
        int gh = h0 - 1 + r, gw = w0 - 1 + cc;
        uint4 v = make_uint4(0u, 0u, 0u, 0u);
        if ((unsigned)gh < HGT && (unsigned)gw < WID)
            v = *(const uint4*)(xn + ((size_t)gh * WID + gw) * CIN + chunk * 8);
        xs[pl * 8 + (chunk ^ (pl & 7))] = v;
    }
    __syncthreads();                            // halo + chunk0 ready

    const int nn = lane & 31;                   // pixel col within row-frag
    const int kh = lane >> 5;                   // ch-half for A/B operands

    const char* xsb = (const char*)xs;
    const unsigned abase = (unsigned)(wmf * 1024 + lane * 16);  // + dy*4096 imm
    const int plb = (wr * 4) * 34 + nn;         // pl at rr=0, dx=0

    f32x16 acc[4];
    #pragma unroll
    for (int b = 0; b < 4; ++b)
        #pragma unroll
        for (int r = 0; r < 16; ++r) acc[b][r] = 0.0f;

    #pragma unroll
    for (int p = 0; p < 12; ++p) {              // p = cs*3 + dx
        const int cs = p / 3, dx = p % 3;
        // ---- prefetch next chunk into the other buffer (no hazard vs readers) ----
        if (p < 11)
            STAGE(p + 1, wl[(p + 1) & 1]);
        const char* wlb = (const char*)wl[p & 1];
        // A: 3 taps (dy) for this (cs,dx) from W-LDS, immediate dy offsets
        bf16x8 A[3];
        #pragma unroll
        for (int dy = 0; dy < 3; ++dy)
            A[dy] = *(const bf16x8*)(wlb + abase + (unsigned)(dy * 4096));
        // B: 6 halo rows at this dx; swizzled byte addr computed inline
        const int chb = cs * 2 + kh;
        bf16x8 B[6];
        #pragma unroll
        for (int rr = 0; rr < 6; ++rr) {
            const int pl = plb + rr * 34 + dx;
            B[rr] = *(const bf16x8*)(xsb + (pl * 128 + (((pl & 7) ^ chb) * 16)));
        }
        // 12 MFMAs, acc reuse distance 4
        __builtin_amdgcn_s_setprio(1);
        #pragma unroll
        for (int dy = 0; dy < 3; ++dy) {
            #pragma unroll
            for (int nf = 0; nf < 4; ++nf) {
                acc[nf] = __builtin_amdgcn_mfma_f32_32x32x16_bf16(A[dy], B[nf + dy], acc[nf], 0, 0, 0);
            }
        }
        __builtin_amdgcn_s_setprio(0);
        __syncthreads();                        // drains this phase's prefetch (hot)
    }
    #undef STAGE

    // ---- epilogue: BN + ReLU + uint8 quant-dequant, LDS repack -> float4 ----
    float* rep = ((float*)xs) + wave * 1024;    // per-wave 4 KB region, no sharing

    // hoist BN scale/shift into registers
    float scr[16], shr[16];
    #pragma unroll
    for (int reg = 0; reg < 16; ++reg) {
        int k = wmf * 32 + 4 * kh + (reg & 3) + 8 * (reg >> 2);
        scr[reg] = sc2[k];
        shr[reg] = sh2[k];
    }

    #pragma unroll
    for (int nf = 0; nf < 4; ++nf) {
        const int hpix = h0 + wr * 4 + nf;
        // write 16 quantized results into swizzled repack tile [32k][32w]
        #pragma unroll
        for (int reg = 0; reg < 16; ++reg) {
            const int kl = 4 * kh + (reg & 3) + 8 * (reg >> 2);
            float t = fmaf(acc[nf][reg], scr[reg], shr[reg]);
            t = fmaxf(t, 0.0f);                                 // relu
            float q = fminf(rintf(t), 255.0f) * s_act;
            rep[kl * 32 + ((((nn >> 2) ^ (kl & 7)) << 2) | (nn & 3))] = q;
        }
        // read back as float4 (4 consecutive w per lane) and store coalesced
        #pragma unroll
        for (int r = 0; r < 4; ++r) {
            const int row = 8 * r + (lane >> 3);                // = kl
            f32x4v v = *(const f32x4v*)&rep[row * 32 + ((((lane & 7) ^ (row & 7)) << 2))];
            const int k = wmf * 32 + row;
            float* dst = out + (((size_t)n * KOUT + k) * HGT + hpix) * WID
                             + w0 + ((lane & 7) << 2);
            *(f32x4v*)dst = v;
        }
    }
}

// ---------------- fallback (fp32 path, used only if ws too small) -----------
#define CB 4
#define TH 8
#define KB 8
__global__ __launch_bounds__(256) void conv_fallback(
    const float* __restrict__ x, const float* __restrict__ W,
    const float* __restrict__ gamma, const float* __restrict__ beta,
    const float* __restrict__ mean, const float* __restrict__ var,
    const float* __restrict__ act_scale, const unsigned* __restrict__ wsmax,
    float* __restrict__ out)
{
    __shared__ float xsf[CB][TH + 2][WID + 2];
    __shared__ float wsh[CB][9][KB];
    const int bid = blockIdx.x;
    const int hg = bid & 15, kg = (bid >> 4) & 15, n = bid >> 8;
    const int h0 = hg * TH, k0 = kg * KB;
    const int tid = threadIdx.x;
    const int tx = tid & 31, ty = tid >> 5;
    float acc[4][KB];
    #pragma unroll
    for (int j = 0; j < 4; ++j)
        #pragma unroll
        for (int kk = 0; kk < KB; ++kk) acc[j][kk] = 0.f;
    const float w_scale = __uint_as_float(*wsmax) / 127.0f;
    const float* xn = x + (size_t)n * CIN * HGT * WID;
    for (int c0 = 0; c0 < CIN; c0 += CB) {
        __syncthreads();
        for (int i = tid; i < CB * (TH + 2) * (WID + 2); i += 256) {
            int cc = i / ((TH + 2) * (WID + 2));
            int r  = i - cc * ((TH + 2) * (WID + 2));
            int yy = r / (WID + 2);
            int xx = r - yy * (WID + 2);
            int gh = h0 - 1 + yy, gw = xx - 1;
            float v = 0.f;
            if ((unsigned)gh < HGT && (unsigned)gw < WID)
                v = xn[(size_t)(c0 + cc) * HGT * WID + gh * WID + gw];
            xsf[cc][yy][xx] = v;
        }
        for (int i = tid; i < CB * 9 * KB; i += 256) {
            int cc = i / (9 * KB);
            int r  = i - cc * (9 * KB);
            int tap = r / KB, kk = r - tap * KB;
            float w = W[(size_t)((k0 + kk) * CIN + (c0 + cc)) * 9 + tap];
            float q = rintf(w / w_scale);
            q = fminf(fmaxf(q, -127.f), 127.f);
            wsh[cc][tap][kk] = q * w_scale;
        }
        __syncthreads();
        #pragma unroll
        for (int cc = 0; cc < CB; ++cc)
            #pragma unroll
            for (int dy = 0; dy < 3; ++dy) {
                float w0a[KB], w1a[KB], w2a[KB];
                #pragma unroll
                for (int kk = 0; kk < KB; ++kk) {
                    w0a[kk] = wsh[cc][dy * 3 + 0][kk];
                    w1a[kk] = wsh[cc][dy * 3 + 1][kk];
                    w2a[kk] = wsh[cc][dy * 3 + 2][kk];
                }
                const float* row = &xsf[cc][ty + dy][0];
                #pragma unroll
                for (int j = 0; j < 4; ++j) {
                    float v0 = row[tx + 32 * j + 0];
                    float v1 = row[tx + 32 * j + 1];
                    float v2 = row[tx + 32 * j + 2];
                    #pragma unroll
                    for (int kk = 0; kk < KB; ++kk) {
                        acc[j][kk] = fmaf(v0, w0a[kk], acc[j][kk]);
                        acc[j][kk] = fmaf(v1, w1a[kk], acc[j][kk]);
                        acc[j][kk] = fmaf(v2, w2a[kk], acc[j][kk]);
                    }
                }
            }
    }
    const float s_act = act_scale[0] / 255.0f;
    const float inv_s = 1.0f / s_act;
    const int h = h0 + ty;
    #pragma unroll
    for (int kk = 0; kk < KB; ++kk) {
        int k = k0 + kk;
        float isd = 1.0f / sqrtf(var[k] + BN_EPS);
        float sc = gamma[k] * isd;
        float sh = beta[k] - gamma[k] * mean[k] * isd;
        float* orow = out + (((size_t)n * KOUT + k) * HGT + h) * WID;
        #pragma unroll
        for (int j = 0; j < 4; ++j) {
            float y = fmaf(acc[j][kk], sc, sh);
            y = fmaxf(y, 0.f);
            float q = rintf(y * inv_s);
            q = fminf(q, 255.f);
            orow[tx + 32 * j] = q * s_act;
        }
    }
}

extern "C" void kernel_launch(void* const* d_in, const int* in_sizes, int n_in,
                              void* d_out, int out_size, void* d_ws, size_t ws_size,
                              hipStream_t stream) {
    const float* x         = (const float*)d_in[0];
    const float* W         = (const float*)d_in[1];
    const float* gamma     = (const float*)d_in[2];
    const float* beta      = (const float*)d_in[3];
    const float* mean      = (const float*)d_in[4];
    const float* var       = (const float*)d_in[5];
    const float* act_scale = (const float*)d_in[6];
    unsigned* wsmax = (unsigned*)d_ws;

    hipMemsetAsync(d_ws, 0, sizeof(unsigned), stream);
    wmax_kernel<<<72, 256, 0, stream>>>(W, wsmax);

    if (ws_size >= WS_NEED) {
        __bf16* wqp = (__bf16*)((char*)d_ws + WQ_OFF);
        __bf16* xT  = (__bf16*)((char*)d_ws + XT_OFF);
        pack_w<<<36, 256, 0, stream>>>(W, wsmax, wqp);
        xform<<<NBATCH * HGT * 4, 256, 0, stream>>>(x, xT);
        conv_mfma<<<NBATCH * 64, 512, 0, stream>>>(
            xT, wqp, gamma, beta, mean, var, act_scale, wsmax, (float*)d_out);
    } else {
        conv_fallback<<<4096, 256, 0, stream>>>(
            x, W, gamma, beta, mean, var, act_scale, wsmax, (float*)d_out);
    }
}

// Round 11
// 101.660 us; speedup vs baseline: 1.0018x; 1.0018x over previous
//
#include <hip/hip_runtime.h>
#include <math.h>

typedef __bf16 bf16x8 __attribute__((ext_vector_type(8)));
typedef float  f32x16 __attribute__((ext_vector_type(16)));
typedef float  f32x4v __attribute__((ext_vector_type(4)));

#define CIN    64
#define KOUT   128
#define HGT    128
#define WID    128
#define NBATCH 16
#define BN_EPS 1e-5f

// workspace layout
#define WQ_OFF   256u                        // packed frag weights: 144*64*16B = 147456 B
#define XT_OFF   (1u << 20)                  // NHWC bf16 x: 16*128*128*64*2 = 33554432 B
#define WS_NEED  ((size_t)XT_OFF + (size_t)NBATCH * HGT * WID * CIN * 2)

// ---------------- w_scale = max|W| ------------------------------------------
__global__ __launch_bounds__(256) void wmax_kernel(const float* __restrict__ W,
                                                   unsigned* __restrict__ wsmax) {
    int idx = blockIdx.x * 256 + threadIdx.x;   // 72*256*4 = 73728 floats
    const float4* W4 = (const float4*)W;
    float4 v = W4[idx];
    float m = fmaxf(fmaxf(fabsf(v.x), fabsf(v.y)), fmaxf(fabsf(v.z), fabsf(v.w)));
    #pragma unroll
    for (int off = 32; off > 0; off >>= 1)
        m = fmaxf(m, __shfl_xor(m, off));
    __shared__ float red[4];
    if ((threadIdx.x & 63) == 0) red[threadIdx.x >> 6] = m;
    __syncthreads();
    if (threadIdx.x == 0) {
        m = fmaxf(fmaxf(red[0], red[1]), fmaxf(red[2], red[3]));
        atomicMax(wsmax, __float_as_uint(m));
    }
}

// ---------------- pack weights into MFMA A-fragment order -------------------
// chunk = cs*3 + dx (12 chunks of 12288 B = 768 uint4, gload_lds-stageable).
// frag index within chunk = dy*4 + mf. Global frag f = ((cs*3+dx)*3 + dy)*4 + mf.
// Lane layout per frag (bf16x8): j-th elem = Wq[kout = mf*32 + (lane&31)]
//                                            [c = cs*16 + (lane>>5)*8 + j] at tap (dy,dx).
__global__ __launch_bounds__(256) void pack_w(const float* __restrict__ W,
                                              const unsigned* __restrict__ wsmax,
                                              __bf16* __restrict__ wqp) {
    int bid = blockIdx.x;                       // 36 = cs*9 + tap
    int tap = bid % 9, cs = bid / 9;
    int dy = tap / 3, dx = tap % 3;
    int t = threadIdx.x;
    int lane = t & 63, mf = t >> 6;
    float ws = __uint_as_float(*wsmax) / 127.0f;
    int kout  = mf * 32 + (lane & 31);
    int cbase = cs * 16 + (lane >> 5) * 8;
    bf16x8 o;
    #pragma unroll
    for (int j = 0; j < 8; ++j) {
        float w = W[(size_t)(kout * 64 + cbase + j) * 9 + tap];
        float q = rintf(w / ws);                // RNE == jnp.round
        q = fminf(fmaxf(q, -127.f), 127.f);
        o[j] = (__bf16)q;                       // integer: exact in bf16
    }
    int f = ((cs * 3 + dx) * 3 + dy) * 4 + mf;
    *(bf16x8*)(wqp + ((size_t)f * 64 + lane) * 8) = o;
}

// ---------------- x: NCHW f32 -> NHWC bf16 -----------------------------------
__global__ __launch_bounds__(256) void xform(const float* __restrict__ x,
                                             __bf16* __restrict__ xT) {
    __shared__ float t[CIN * 32];               // 8 KB, xor-swizzled cols
    int bid = blockIdx.x;                       // n*512 + h*4 + wt
    int wt = bid & 3;
    int h  = (bid >> 2) & 127;
    int n  = bid >> 9;
    int w0 = wt * 32;
    int tid = threadIdx.x;
    const float* src = x + ((size_t)n * CIN * HGT + h) * WID + w0;
    int wlane = tid & 31;
    int cbase = tid >> 5;
    #pragma unroll
    for (int it = 0; it < 8; ++it) {
        int c = cbase + it * 8;
        t[c * 32 + (wlane ^ (c & 31))] = src[(size_t)c * HGT * WID + wlane];
    }
    __syncthreads();
    int w = tid >> 3;
    int chunk = tid & 7;
    bf16x8 o;
    #pragma unroll
    for (int j = 0; j < 8; ++j) {
        int c = chunk * 8 + j;
        o[j] = (__bf16)t[c * 32 + (w ^ (c & 31))];
    }
    *(bf16x8*)(xT + (((size_t)n * HGT + h) * WID + w0 + w) * CIN + chunk * 8) = o;
}

// ---------------- conv3x3 via MFMA 32x32x16 bf16 ----------------------------
// block: 512 thr = 8 waves; out tile 8h x 32w x 128 kout; 2 blocks/CU (69 KB LDS).
// 12-phase pipeline (phase = cs*3+dx): weight chunk (p+1) prefetched into the
// OTHER LDS buffer via global_load_lds while phase p computes -> barrier never
// drains a cold load (T3-lite / m97 structure). Accumulation order unchanged.
__global__ __launch_bounds__(512, 4) void conv_mfma(
    const __bf16* __restrict__ xT, const __bf16* __restrict__ wqp,
    const float* __restrict__ gamma, const float* __restrict__ beta,
    const float* __restrict__ mean, const float* __restrict__ var,
    const float* __restrict__ act_scale, const unsigned* __restrict__ wsmax,
    float* __restrict__ out)
{
    __shared__ uint4 xs[2720];                  // halo 43520 B; reused as repack buf
    __shared__ uint4 wl[2][768];                // weight chunk dbuf: 24576 B
    __shared__ float sc2[KOUT], sh2[KOUT];      // 1024 B   (total 69120 B -> 2 blk/CU)

    // XCD-bijective swizzle: nwg = 1024, 8 XCDs, 1024 % 8 == 0
    const int bid0 = blockIdx.x;
    const int bid  = (bid0 & 7) * 128 + (bid0 >> 3);
    const int wb = bid & 3, hb = (bid >> 2) & 15, n = bid >> 6;
    const int h0 = hb * 8, w0 = wb * 32;
    const int tid  = threadIdx.x;
    const int lane = tid & 63;
    const int wave = tid >> 6;
    const int wmf = wave & 3;                   // kout frag (32 kout)
    const int wr  = wave >> 2;                  // row group (4 rows)

    const uint4* wq4 = (const uint4*)wqp;
    // stage chunk c (768 uint4) into buf: 12 x gload_lds of 1 KB (64 lanes x 16B)
    #define STAGE(c, buf)                                                          \
      do {                                                                         \
        const uint4* _src = wq4 + (size_t)(c) * 768;                               \
        uint4* _dst = (buf);                                                       \
        __builtin_amdgcn_global_load_lds((const void*)(_src + wave * 64 + lane),   \
                                         (void*)(_dst + wave * 64), 16, 0, 0);     \
        if (wave < 4)                                                              \
          __builtin_amdgcn_global_load_lds(                                        \
              (const void*)(_src + (8 + wave) * 64 + lane),                        \
              (void*)(_dst + (8 + wave) * 64), 16, 0, 0);                          \
      } while (0)

    // ---- prologue: issue chunk-0 prefetch FIRST (in flight under halo staging) ----
    STAGE(0, wl[0]);

    const float s_act = act_scale[0] / 255.0f;
    if (tid < KOUT) {
        float ws  = __uint_as_float(*wsmax) / 127.0f;
        float isd = 1.0f / sqrtf(var[tid] + BN_EPS);
        float sc  = ws * gamma[tid] * isd;      // fold w_scale into BN scale
        float sh  = beta[tid] - gamma[tid] * mean[tid] * isd;
        sc2[tid] = sc / s_act;                  // q = rint(acc*sc2 + sh2)
        sh2[tid] = sh / s_act;
    }

    // ---- stage halo tile 10 x 34 px x 64 ch, chunk-xor swizzle (write==read) ----
    const __bf16* xn = xT + (size_t)n * HGT * WID * CIN;
    for (int it = tid; it < 2720; it += 512) {
        int pl = it >> 3, chunk = it & 7;
        int r = pl / 34, cc = pl - r * 34;
        int gh = h0 - 1 + r, gw = w0 - 1 + cc;
        uint4 v = make_uint4(0u, 0u, 0u, 0u);
        if ((unsigned)gh < HGT && (unsigned)gw < WID)
            v = *(const uint4*)(xn + ((size_t)gh * WID + gw) * CIN + chunk * 8);
        xs[pl * 8 + (chunk ^ (pl & 7))] = v;
    }
    __syncthreads();                            // halo + chunk0 ready

    const int nn = lane & 31;                   // pixel col within row-frag
    const int kh = lane >> 5;                   // ch-half for A/B operands

    const char* xsb = (const char*)xs;
    const unsigned abase = (unsigned)(wmf * 1024 + lane * 16);  // + dy*4096 imm
    const int plb = (wr * 4) * 34 + nn;         // pl at rr=0, dx=0

    f32x16 acc[4];
    #pragma unroll
    for (int b = 0; b < 4; ++b)
        #pragma unroll
        for (int r = 0; r < 16; ++r) acc[b][r] = 0.0f;

    #pragma unroll
    for (int p = 0; p < 12; ++p) {              // p = cs*3 + dx
        const int cs = p / 3, dx = p % 3;
        // ---- prefetch next chunk into the other buffer (no hazard vs readers) ----
        if (p < 11)
            STAGE(p + 1, wl[(p + 1) & 1]);
        const char* wlb = (const char*)wl[p & 1];
        // A: 3 taps (dy) for this (cs,dx) from W-LDS, immediate dy offsets
        bf16x8 A[3];
        #pragma unroll
        for (int dy = 0; dy < 3; ++dy)
            A[dy] = *(const bf16x8*)(wlb + abase + (unsigned)(dy * 4096));
        // B: 6 halo rows at this dx; swizzled byte addr computed inline
        const int chb = cs * 2 + kh;
        bf16x8 B[6];
        #pragma unroll
        for (int rr = 0; rr < 6; ++rr) {
            const int pl = plb + rr * 34 + dx;
            B[rr] = *(const bf16x8*)(xsb + (pl * 128 + (((pl & 7) ^ chb) * 16)));
        }
        // 12 MFMAs, acc reuse distance 4
        __builtin_amdgcn_s_setprio(1);
        #pragma unroll
        for (int dy = 0; dy < 3; ++dy) {
            #pragma unroll
            for (int nf = 0; nf < 4; ++nf) {
                acc[nf] = __builtin_amdgcn_mfma_f32_32x32x16_bf16(A[dy], B[nf + dy], acc[nf], 0, 0, 0);
            }
        }
        __builtin_amdgcn_s_setprio(0);
        __syncthreads();                        // drains this phase's prefetch (hot)
    }
    #undef STAGE

    // ---- epilogue: BN + ReLU + uint8 quant-dequant, LDS repack -> float4 ----
    float* rep = ((float*)xs) + wave * 1024;    // per-wave 4 KB region, no sharing

    // hoist BN scale/shift into registers
    float scr[16], shr[16];
    #pragma unroll
    for (int reg = 0; reg < 16; ++reg) {
        int k = wmf * 32 + 4 * kh + (reg & 3) + 8 * (reg >> 2);
        scr[reg] = sc2[k];
        shr[reg] = sh2[k];
    }

    #pragma unroll
    for (int nf = 0; nf < 4; ++nf) {
        const int hpix = h0 + wr * 4 + nf;
        // write 16 quantized results into swizzled repack tile [32k][32w]
        #pragma unroll
        for (int reg = 0; reg < 16; ++reg) {
            const int kl = 4 * kh + (reg & 3) + 8 * (reg >> 2);
            float t = fmaf(acc[nf][reg], scr[reg], shr[reg]);
            t = fmaxf(t, 0.0f);                                 // relu
            float q = fminf(rintf(t), 255.0f) * s_act;
            rep[kl * 32 + ((((nn >> 2) ^ (kl & 7)) << 2) | (nn & 3))] = q;
        }
        // read back as float4 (4 consecutive w per lane) and store coalesced
        #pragma unroll
        for (int r = 0; r < 4; ++r) {
            const int row = 8 * r + (lane >> 3);                // = kl
            f32x4v v = *(const f32x4v*)&rep[row * 32 + ((((lane & 7) ^ (row & 7)) << 2))];
            const int k = wmf * 32 + row;
            float* dst = out + (((size_t)n * KOUT + k) * HGT + hpix) * WID
                             + w0 + ((lane & 7) << 2);
            *(f32x4v*)dst = v;
        }
    }
}

// ---------------- fallback (fp32 path, used only if ws too small) -----------
#define CB 4
#define TH 8
#define KB 8
__global__ __launch_bounds__(256) void conv_fallback(
    const float* __restrict__ x, const float* __restrict__ W,
    const float* __restrict__ gamma, const float* __restrict__ beta,
    const float* __restrict__ mean, const float* __restrict__ var,
    const float* __restrict__ act_scale, const unsigned* __restrict__ wsmax,
    float* __restrict__ out)
{
    __shared__ float xsf[CB][TH + 2][WID + 2];
    __shared__ float wsh[CB][9][KB];
    const int bid = blockIdx.x;
    const int hg = bid & 15, kg = (bid >> 4) & 15, n = bid >> 8;
    const int h0 = hg * TH, k0 = kg * KB;
    const int tid = threadIdx.x;
    const int tx = tid & 31, ty = tid >> 5;
    float acc[4][KB];
    #pragma unroll
    for (int j = 0; j < 4; ++j)
        #pragma unroll
        for (int kk = 0; kk < KB; ++kk) acc[j][kk] = 0.f;
    const float w_scale = __uint_as_float(*wsmax) / 127.0f;
    const float* xn = x + (size_t)n * CIN * HGT * WID;
    for (int c0 = 0; c0 < CIN; c0 += CB) {
        __syncthreads();
        for (int i = tid; i < CB * (TH + 2) * (WID + 2); i += 256) {
            int cc = i / ((TH + 2) * (WID + 2));
            int r  = i - cc * ((TH + 2) * (WID + 2));
            int yy = r / (WID + 2);
            int xx = r - yy * (WID + 2);
            int gh = h0 - 1 + yy, gw = xx - 1;
            float v = 0.f;
            if ((unsigned)gh < HGT && (unsigned)gw < WID)
                v = xn[(size_t)(c0 + cc) * HGT * WID + gh * WID + gw];
            xsf[cc][yy][xx] = v;
        }
        for (int i = tid; i < CB * 9 * KB; i += 256) {
            int cc = i / (9 * KB);
            int r  = i - cc * (9 * KB);
            int tap = r / KB, kk = r - tap * KB;
            float w = W[(size_t)((k0 + kk) * CIN + (c0 + cc)) * 9 + tap];
            float q = rintf(w / w_scale);
            q = fminf(fmaxf(q, -127.f), 127.f);
            wsh[cc][tap][kk] = q * w_scale;
        }
        __syncthreads();
        #pragma unroll
        for (int cc = 0; cc < CB; ++cc)
            #pragma unroll
            for (int dy = 0; dy < 3; ++dy) {
                float w0a[KB], w1a[KB], w2a[KB];
                #pragma unroll
                for (int kk = 0; kk < KB; ++kk) {
                    w0a[kk] = wsh[cc][dy * 3 + 0][kk];
                    w1a[kk] = wsh[cc][dy * 3 + 1][kk];
                    w2a[kk] = wsh[cc][dy * 3 + 2][kk];
                }
                const float* row = &xsf[cc][ty + dy][0];
                #pragma unroll
                for (int j = 0; j < 4; ++j) {
                    float v0 = row[tx + 32 * j + 0];
                    float v1 = row[tx + 32 * j + 1];
                    float v2 = row[tx + 32 * j + 2];
                    #pragma unroll
                    for (int kk = 0; kk < KB; ++kk) {
                        acc[j][kk] = fmaf(v0, w0a[kk], acc[j][kk]);
                        acc[j][kk] = fmaf(v1, w1a[kk], acc[j][kk]);
                        acc[j][kk] = fmaf(v2, w2a[kk], acc[j][kk]);
                    }
                }
            }
    }
    const float s_act = act_scale[0] / 255.0f;
    const float inv_s = 1.0f / s_act;
    const int h = h0 + ty;
    #pragma unroll
    for (int kk = 0; kk < KB; ++kk) {
        int k = k0 + kk;
        float isd = 1.0f / sqrtf(var[k] + BN_EPS);
        float sc = gamma[k] * isd;
        float sh = beta[k] - gamma[k] * mean[k] * isd;
        float* orow = out + (((size_t)n * KOUT + k) * HGT + h) * WID;
        #pragma unroll
        for (int j = 0; j < 4; ++j) {
            float y = fmaf(acc[j][kk], sc, sh);
            y = fmaxf(y, 0.f);
            float q = rintf(y * inv_s);
            q = fminf(q, 255.f);
            orow[tx + 32 * j] = q * s_act;
        }
    }
}

extern "C" void kernel_launch(void* const* d_in, const int* in_sizes, int n_in,
                              void* d_out, int out_size, void* d_ws, size_t ws_size,
                              hipStream_t stream) {
    const float* x         = (const float*)d_in[0];
    const float* W         = (const float*)d_in[1];
    const float* gamma     = (const float*)d_in[2];
    const float* beta      = (const float*)d_in[3];
    const float* mean      = (const float*)d_in[4];
    const float* var       = (const float*)d_in[5];
    const float* act_scale = (const float*)d_in[6];
    unsigned* wsmax = (unsigned*)d_ws;

    hipMemsetAsync(d_ws, 0, sizeof(unsigned), stream);
    wmax_kernel<<<72, 256, 0, stream>>>(W, wsmax);

    if (ws_size >= WS_NEED) {
        __bf16* wqp = (__bf16*)((char*)d_ws + WQ_OFF);
        __bf16* xT  = (__bf16*)((char*)d_ws + XT_OFF);
        pack_w<<<36, 256, 0, stream>>>(W, wsmax, wqp);
        xform<<<NBATCH * HGT * 4, 256, 0, stream>>>(x, xT);
        conv_mfma<<<NBATCH * 64, 512, 0, stream>>>(
            xT, wqp, gamma, beta, mean, var, act_scale, wsmax, (float*)d_out);
    } else {
        conv_fallback<<<4096, 256, 0, stream>>>(
            x, W, gamma, beta, mean, var, act_scale, wsmax, (float*)d_out);
    }
}

// Round 12
// 78.375 us; speedup vs baseline: 1.2995x; 1.2971x over previous
//
#include <hip/hip_runtime.h>
#include <math.h>

typedef __bf16 bf16x8 __attribute__((ext_vector_type(8)));
typedef float  f32x16 __attribute__((ext_vector_type(16)));
typedef float  f32x4v __attribute__((ext_vector_type(4)));

#define CIN    64
#define KOUT   128
#define HGT    128
#define WID    128
#define NBATCH 16
#define BN_EPS 1e-5f

// workspace layout (xT eliminated: conv reads NCHW x directly)
#define WQ_OFF   256u                        // packed frag weights: 36*4*64*16B = 147456 B
#define WS_NEED  ((size_t)WQ_OFF + 147456u)

// ---------------- w_scale = max|W| ------------------------------------------
__global__ __launch_bounds__(256) void wmax_kernel(const float* __restrict__ W,
                                                   unsigned* __restrict__ wsmax) {
    int idx = blockIdx.x * 256 + threadIdx.x;   // 72*256*4 = 73728 floats
    const float4* W4 = (const float4*)W;
    float4 v = W4[idx];
    float m = fmaxf(fmaxf(fabsf(v.x), fabsf(v.y)), fmaxf(fabsf(v.z), fabsf(v.w)));
    #pragma unroll
    for (int off = 32; off > 0; off >>= 1)
        m = fmaxf(m, __shfl_xor(m, off));
    __shared__ float red[4];
    if ((threadIdx.x & 63) == 0) red[threadIdx.x >> 6] = m;
    __syncthreads();
    if (threadIdx.x == 0) {
        m = fmaxf(fmaxf(red[0], red[1]), fmaxf(red[2], red[3]));
        atomicMax(wsmax, __float_as_uint(m));
    }
}

// ---------------- pack weights into MFMA A-fragment order -------------------
// wqp frag index (cs*9+tap)*4 + mf; per-lane bf16x8:
//   j-th elem = Wq[kout = mf*32 + (lane&31)][c = cs*16 + (lane>>5)*8 + j] at tap.
// cs-major: one cs-chunk = 2304 contiguous uint4 (36864 B) -> LDS-stageable.
__global__ __launch_bounds__(256) void pack_w(const float* __restrict__ W,
                                              const unsigned* __restrict__ wsmax,
                                              __bf16* __restrict__ wqp) {
    int bid = blockIdx.x;                       // 36 = cs*9 + tap
    int tap = bid % 9, cs = bid / 9;
    int t = threadIdx.x;
    int lane = t & 63, mf = t >> 6;
    float ws = __uint_as_float(*wsmax) / 127.0f;
    int kout  = mf * 32 + (lane & 31);
    int cbase = cs * 16 + (lane >> 5) * 8;
    bf16x8 o;
    #pragma unroll
    for (int j = 0; j < 8; ++j) {
        float w = W[(size_t)(kout * 64 + cbase + j) * 9 + tap];
        float q = rintf(w / ws);                // RNE == jnp.round
        q = fminf(fmaxf(q, -127.f), 127.f);
        o[j] = (__bf16)q;                       // integer: exact in bf16
    }
    *(bf16x8*)(wqp + (((size_t)bid * 4 + mf) * 64 + lane) * 8) = o;
    (void)cs;
}

// ---------------- conv3x3 via MFMA 32x32x16 bf16 (fused NCHW gather) --------
// block: 512 thr = 8 waves; out tile 8h x 32w x 128 kout; 2 blocks/CU (81 KB LDS).
// Prologue gathers the halo straight from NCHW f32 x (8 scalar dwords per 16B
// LDS write, RNE f32->bf16 cast == xform's) -> xform kernel + 98 MB intermediate
// traffic eliminated. Compute/staging/epilogue = round-9 structure (best measured).
__global__ __launch_bounds__(512, 4) void conv_mfma(
    const float* __restrict__ x, const __bf16* __restrict__ wqp,
    const float* __restrict__ gamma, const float* __restrict__ beta,
    const float* __restrict__ mean, const float* __restrict__ var,
    const float* __restrict__ act_scale, const unsigned* __restrict__ wsmax,
    float* __restrict__ out)
{
    __shared__ uint4 xs[2720];                  // halo 43520 B; reused as repack buf
    __shared__ uint4 wl[2304];                  // weight cs-chunk: 36864 B
    __shared__ float sc2[KOUT], sh2[KOUT];      // 1024 B   (total 81408 B -> 2 blk/CU)

    // XCD-bijective swizzle: nwg = 1024, 8 XCDs, 1024 % 8 == 0
    const int bid0 = blockIdx.x;
    const int bid  = (bid0 & 7) * 128 + (bid0 >> 3);
    const int wb = bid & 3, hb = (bid >> 2) & 15, n = bid >> 6;
    const int h0 = hb * 8, w0 = wb * 32;
    const int tid  = threadIdx.x;
    const int lane = tid & 63;
    const int wave = tid >> 6;
    const int wmf = wave & 3;                   // kout frag (32 kout)
    const int wr  = wave >> 2;                  // row group (4 rows)

    const float s_act = act_scale[0] / 255.0f;
    if (tid < KOUT) {
        float ws  = __uint_as_float(*wsmax) / 127.0f;
        float isd = 1.0f / sqrtf(var[tid] + BN_EPS);
        float sc  = ws * gamma[tid] * isd;      // fold w_scale into BN scale
        float sh  = beta[tid] - gamma[tid] * mean[tid] * isd;
        sc2[tid] = sc / s_act;                  // q = rint(acc*sc2 + sh2)
        sh2[tid] = sh / s_act;
    }

    // ---- fused halo gather: NCHW f32 -> bf16, chunk-xor swizzled LDS ----
    // i = chunk*340 + pl: lanes sweep pl -> consecutive gw (coalesced 34-runs).
    const float* xnf = x + (size_t)n * CIN * HGT * WID;
    for (int i = tid; i < 2720; i += 512) {
        int chunk = i / 340;                    // 0..7 (8 channels each)
        int pl    = i - chunk * 340;            // 0..339
        int r = pl / 34, cc = pl - r * 34;
        int gh = h0 - 1 + r, gw = w0 - 1 + cc;
        bf16x8 v;
        if ((unsigned)gh < HGT && (unsigned)gw < WID) {
            const float* s = xnf + (size_t)(chunk * 8) * (HGT * WID) + gh * WID + gw;
            #pragma unroll
            for (int j = 0; j < 8; ++j)
                v[j] = (__bf16)s[(size_t)j * (HGT * WID)];   // RNE, == xform cast
        } else {
            #pragma unroll
            for (int j = 0; j < 8; ++j)
                v[j] = (__bf16)0.0f;
        }
        *(bf16x8*)((char*)xs + (pl * 128 + ((chunk ^ (pl & 7)) * 16))) = v;
    }
    // ---- stage weight chunk cs=0 ----
    const uint4* wq4 = (const uint4*)wqp;
    for (int i = tid; i < 2304; i += 512)
        wl[i] = wq4[i];
    __syncthreads();

    const int nn = lane & 31;                   // pixel col within row-frag
    const int kh = lane >> 5;                   // ch-half for A/B operands

    const char* xsb = (const char*)xs;
    const char* wlb = (const char*)wl;
    const unsigned abase = (unsigned)(wmf * 1024 + lane * 16);  // + tap*4096 imm
    const int plb = (wr * 4) * 34 + nn;         // pl at rr=0, dx=0

    f32x16 acc[4];
    #pragma unroll
    for (int b = 0; b < 4; ++b)
        #pragma unroll
        for (int r = 0; r < 16; ++r) acc[b][r] = 0.0f;

    for (int cs = 0; cs < 4; ++cs) {
        if (cs) {
            __syncthreads();                    // wl readers of cs-1 done
            for (int i = tid; i < 2304; i += 512)
                wl[i] = wq4[(size_t)cs * 2304 + i];
            __syncthreads();
        }
        const int chb = cs * 2 + kh;
        #pragma unroll
        for (int dx = 0; dx < 3; ++dx) {
            // A: 3 taps (dy) from W-LDS, immediate tap offsets
            bf16x8 A[3];
            #pragma unroll
            for (int dy = 0; dy < 3; ++dy)
                A[dy] = *(const bf16x8*)(wlb + abase + (unsigned)((dy * 3 + dx) * 4096));
            // B: 6 halo rows at this dx; swizzled byte addr computed inline
            bf16x8 B[6];
            #pragma unroll
            for (int rr = 0; rr < 6; ++rr) {
                const int pl = plb + rr * 34 + dx;
                B[rr] = *(const bf16x8*)(xsb + (pl * 128 + (((pl & 7) ^ chb) * 16)));
            }
            // 12 MFMAs, acc reuse distance 4
            #pragma unroll
            for (int dy = 0; dy < 3; ++dy) {
                #pragma unroll
                for (int nf = 0; nf < 4; ++nf) {
                    acc[nf] = __builtin_amdgcn_mfma_f32_32x32x16_bf16(A[dy], B[nf + dy], acc[nf], 0, 0, 0);
                }
            }
        }
    }

    // ---- epilogue: BN + ReLU + uint8 quant-dequant, LDS repack -> float4 ----
    __syncthreads();                            // all xs halo readers done
    float* rep = ((float*)xs) + wave * 1024;    // per-wave 4 KB region, no sharing

    // hoist BN scale/shift into registers
    float scr[16], shr[16];
    #pragma unroll
    for (int reg = 0; reg < 16; ++reg) {
        int k = wmf * 32 + 4 * kh + (reg & 3) + 8 * (reg >> 2);
        scr[reg] = sc2[k];
        shr[reg] = sh2[k];
    }

    #pragma unroll
    for (int nf = 0; nf < 4; ++nf) {
        const int hpix = h0 + wr * 4 + nf;
        // write 16 quantized results into swizzled repack tile [32k][32w]
        #pragma unroll
        for (int reg = 0; reg < 16; ++reg) {
            const int kl = 4 * kh + (reg & 3) + 8 * (reg >> 2);
            float t = fmaf(acc[nf][reg], scr[reg], shr[reg]);
            t = fmaxf(t, 0.0f);                                 // relu
            float q = fminf(rintf(t), 255.0f) * s_act;
            rep[kl * 32 + ((((nn >> 2) ^ (kl & 7)) << 2) | (nn & 3))] = q;
        }
        // read back as float4 (4 consecutive w per lane) and store coalesced
        #pragma unroll
        for (int r = 0; r < 4; ++r) {
            const int row = 8 * r + (lane >> 3);                // = kl
            f32x4v v = *(const f32x4v*)&rep[row * 32 + ((((lane & 7) ^ (row & 7)) << 2))];
            const int k = wmf * 32 + row;
            float* dst = out + (((size_t)n * KOUT + k) * HGT + hpix) * WID
                             + w0 + ((lane & 7) << 2);
            *(f32x4v*)dst = v;
        }
    }
}

// ---------------- fallback (fp32 path, used only if ws too small) -----------
#define CB 4
#define TH 8
#define KB 8
__global__ __launch_bounds__(256) void conv_fallback(
    const float* __restrict__ x, const float* __restrict__ W,
    const float* __restrict__ gamma, const float* __restrict__ beta,
    const float* __restrict__ mean, const float* __restrict__ var,
    const float* __restrict__ act_scale, const unsigned* __restrict__ wsmax,
    float* __restrict__ out)
{
    __shared__ float xsf[CB][TH + 2][WID + 2];
    __shared__ float wsh[CB][9][KB];
    const int bid = blockIdx.x;
    const int hg = bid & 15, kg = (bid >> 4) & 15, n = bid >> 8;
    const int h0 = hg * TH, k0 = kg * KB;
    const int tid = threadIdx.x;
    const int tx = tid & 31, ty = tid >> 5;
    float acc[4][KB];
    #pragma unroll
    for (int j = 0; j < 4; ++j)
        #pragma unroll
        for (int kk = 0; kk < KB; ++kk) acc[j][kk] = 0.f;
    const float w_scale = __uint_as_float(*wsmax) / 127.0f;
    const float* xn = x + (size_t)n * CIN * HGT * WID;
    for (int c0 = 0; c0 < CIN; c0 += CB) {
        __syncthreads();
        for (int i = tid; i < CB * (TH + 2) * (WID + 2); i += 256) {
            int cc = i / ((TH + 2) * (WID + 2));
            int r  = i - cc * ((TH + 2) * (WID + 2));
            int yy = r / (WID + 2);
            int xx = r - yy * (WID + 2);
            int gh = h0 - 1 + yy, gw = xx - 1;
            float v = 0.f;
            if ((unsigned)gh < HGT && (unsigned)gw < WID)
                v = xn[(size_t)(c0 + cc) * HGT * WID + gh * WID + gw];
            xsf[cc][yy][xx] = v;
        }
        for (int i = tid; i < CB * 9 * KB; i += 256) {
            int cc = i / (9 * KB);
            int r  = i - cc * (9 * KB);
            int tap = r / KB, kk = r - tap * KB;
            float w = W[(size_t)((k0 + kk) * CIN + (c0 + cc)) * 9 + tap];
            float q = rintf(w / w_scale);
            q = fminf(fmaxf(q, -127.f), 127.f);
            wsh[cc][tap][kk] = q * w_scale;
        }
        __syncthreads();
        #pragma unroll
        for (int cc = 0; cc < CB; ++cc)
            #pragma unroll
            for (int dy = 0; dy < 3; ++dy) {
                float w0a[KB], w1a[KB], w2a[KB];
                #pragma unroll
                for (int kk = 0; kk < KB; ++kk) {
                    w0a[kk] = wsh[cc][dy * 3 + 0][kk];
                    w1a[kk] = wsh[cc][dy * 3 + 1][kk];
                    w2a[kk] = wsh[cc][dy * 3 + 2][kk];
                }
                const float* row = &xsf[cc][ty + dy][0];
                #pragma unroll
                for (int j = 0; j < 4; ++j) {
                    float v0 = row[tx + 32 * j + 0];
                    float v1 = row[tx + 32 * j + 1];
                    float v2 = row[tx + 32 * j + 2];
                    #pragma unroll
                    for (int kk = 0; kk < KB; ++kk) {
                        acc[j][kk] = fmaf(v0, w0a[kk], acc[j][kk]);
                        acc[j][kk] = fmaf(v1, w1a[kk], acc[j][kk]);
                        acc[j][kk] = fmaf(v2, w2a[kk], acc[j][kk]);
                    }
                }
            }
    }
    const float s_act = act_scale[0] / 255.0f;
    const float inv_s = 1.0f / s_act;
    const int h = h0 + ty;
    #pragma unroll
    for (int kk = 0; kk < KB; ++kk) {
        int k = k0 + kk;
        float isd = 1.0f / sqrtf(var[k] + BN_EPS);
        float sc = gamma[k] * isd;
        float sh = beta[k] - gamma[k] * mean[k] * isd;
        float* orow = out + (((size_t)n * KOUT + k) * HGT + h) * WID;
        #pragma unroll
        for (int j = 0; j < 4; ++j) {
            float y = fmaf(acc[j][kk], sc, sh);
            y = fmaxf(y, 0.f);
            float q = rintf(y * inv_s);
            q = fminf(q, 255.f);
            orow[tx + 32 * j] = q * s_act;
        }
    }
}

extern "C" void kernel_launch(void* const* d_in, const int* in_sizes, int n_in,
                              void* d_out, int out_size, void* d_ws, size_t ws_size,
                              hipStream_t stream) {
    const float* x         = (const float*)d_in[0];
    const float* W         = (const float*)d_in[1];
    const float* gamma     = (const float*)d_in[2];
    const float* beta      = (const float*)d_in[3];
    const float* mean      = (const float*)d_in[4];
    const float* var       = (const float*)d_in[5];
    const float* act_scale = (const float*)d_in[6];
    unsigned* wsmax = (unsigned*)d_ws;

    hipMemsetAsync(d_ws, 0, sizeof(unsigned), stream);
    wmax_kernel<<<72, 256, 0, stream>>>(W, wsmax);

    if (ws_size >= WS_NEED) {
        __bf16* wqp = (__bf16*)((char*)d_ws + WQ_OFF);
        pack_w<<<36, 256, 0, stream>>>(W, wsmax, wqp);
        conv_mfma<<<NBATCH * 64, 512, 0, stream>>>(
            x, wqp, gamma, beta, mean, var, act_scale, wsmax, (float*)d_out);
    } else {
        conv_fallback<<<4096, 256, 0, stream>>>(
            x, W, gamma, beta, mean, var, act_scale, wsmax, (float*)d_out);
    }
}